// Round 4
// baseline (667.783 us; speedup 1.0000x reference)
//
#include <hip/hip_runtime.h>

#define NR   16384
#define CIN  2048
#define VDIM 128
#define SPLITK 4
#define KSL  (CIN / SPLITK)   // 512

#define FMA4(accv, s, bv) { accv.x += (s)*(bv).x; accv.y += (s)*(bv).y; accv.z += (s)*(bv).z; accv.w += (s)*(bv).w; }

// ---------------------------------------------------------------------------
// 1) Normalize columns of Fq -> V [CIN][VDIM] and Vt [VDIM][CIN]
// ---------------------------------------------------------------------------
__global__ __launch_bounds__(256) void k_normalize(const float* __restrict__ Fq,
                                                   float* __restrict__ V,
                                                   float* __restrict__ Vt) {
    int k = blockIdx.x;            // column index
    __shared__ float red[256];
    float ss = 0.f;
    for (int i = threadIdx.x; i < CIN; i += 256) {
        float v = Fq[i * VDIM + k];
        ss += v * v;
    }
    red[threadIdx.x] = ss;
    __syncthreads();
    for (int off = 128; off > 0; off >>= 1) {
        if (threadIdx.x < off) red[threadIdx.x] += red[threadIdx.x + off];
        __syncthreads();
    }
    float inv = 1.0f / sqrtf(red[0]);
    for (int i = threadIdx.x; i < CIN; i += 256) {
        float v = Fq[i * VDIM + k] * inv;
        V[i * VDIM + k] = v;
        Vt[k * CIN + i] = v;
    }
}

// ---------------------------------------------------------------------------
// 2) Gram matrix G[j][k] = v_j . v_k  (symmetric), from Vt rows (contiguous)
// ---------------------------------------------------------------------------
__global__ __launch_bounds__(64) void k_gram(const float* __restrict__ Vt,
                                             float* __restrict__ G) {
    int j = blockIdx.x, k = blockIdx.y;
    int lane = threadIdx.x;
    const float* a = Vt + j * CIN;
    const float* b = Vt + k * CIN;
    float s = 0.f;
    for (int i = lane * 4; i < CIN; i += 64 * 4) {
        float4 av = *(const float4*)(a + i);
        float4 bv = *(const float4*)(b + i);
        s += av.x * bv.x + av.y * bv.y + av.z * bv.z + av.w * bv.w;
    }
    #pragma unroll
    for (int off = 32; off > 0; off >>= 1) s += __shfl_down(s, off, 64);
    if (lane == 0) G[j * VDIM + k] = s;
}

// ---------------------------------------------------------------------------
// 3) W = M^{-1} (2 Vt)  where M = I + 2*strictUpper(G) (unit upper-triang).
//    Descending row recurrence: W[i] = 2Vt[i] - sum_{k>i} 2 G[i][k] W[k].
//    Thread c owns output column c: NO cross-thread deps, no barriers, no
//    shuffles. W-chunk lives in LDS (indexed private column per thread);
//    row-consecutive access -> 2 lanes/bank (free). G reads are uniform ->
//    scalar loads on the SMEM path.
// ---------------------------------------------------------------------------
__global__ __launch_bounds__(128) void k_W(const float* __restrict__ Vt,
                                           const float* __restrict__ G,
                                           float* __restrict__ W) {
    __shared__ float w[VDIM][128];     // 64 KB exactly
    int c = threadIdx.x;               // 0..127
    int cb = blockIdx.x * 128;
    #pragma unroll 4
    for (int k = 0; k < VDIM; ++k)
        w[k][c] = 2.f * Vt[(size_t)k * CIN + cb + c];
    // w[127] is final already
    for (int i = VDIM - 2; i >= 0; --i) {
        const float* gi = G + i * VDIM;
        float a0 = 0.f, a1 = 0.f, a2 = 0.f, a3 = 0.f;
        int k = i + 1;
        for (; k + 3 < VDIM; k += 4) {
            a0 += gi[k + 0] * w[k + 0][c];
            a1 += gi[k + 1] * w[k + 1][c];
            a2 += gi[k + 2] * w[k + 2][c];
            a3 += gi[k + 3] * w[k + 3][c];
        }
        for (; k < VDIM; ++k) a0 += gi[k] * w[k][c];
        w[i][c] -= 2.f * ((a0 + a1) + (a2 + a3));
    }
    #pragma unroll 4
    for (int k = 0; k < VDIM; ++k)
        W[(size_t)k * CIN + cb + c] = w[k][c];
}

// ---------------------------------------------------------------------------
// 4) P_y = x[:, y*512:(y+1)*512] @ V[y*512:(y+1)*512, :]   (split-K partials)
//    128x128 block tile, BK=16, 8x8 register tile, double-buffered LDS.
// ---------------------------------------------------------------------------
__global__ __launch_bounds__(256) void k_P(const float* __restrict__ X,
                                           const float* __restrict__ V,
                                           float* __restrict__ Pp) {
    __shared__ float xs[2][16][132];   // A^T tile [k][row], pad 4
    __shared__ float vs[2][16][132];   // B tile  [k][col], pad 4
    int tid = threadIdx.x;
    int rowbase = blockIdx.x * 128;
    int kstart = blockIdx.y * KSL;
    float* P = Pp + (size_t)blockIdx.y * NR * VDIM;

    int r0 = (tid >> 4) << 2;       // 0..60
    int c0 = (tid & 15) << 2;       // 0..60
    int arow = tid >> 1;            // 0..127
    int aq   = (tid & 1) << 3;      // 0 or 8
    int brow = tid >> 5;            // 0..7
    int bcol = (tid & 31) << 2;     // 0..124

    float4 acc[2][2][4];
    #pragma unroll
    for (int a = 0; a < 2; ++a)
        #pragma unroll
        for (int b = 0; b < 2; ++b)
            #pragma unroll
            for (int i = 0; i < 4; ++i) acc[a][b][i] = make_float4(0.f, 0.f, 0.f, 0.f);

    const float* xsrc = X + (size_t)(rowbase + arow) * CIN + kstart + aq;

    float4 avA, avB, bvA, bvB;
    avA = *(const float4*)(xsrc);
    avB = *(const float4*)(xsrc + 4);
    {
        const float4* vp = (const float4*)(V + (size_t)kstart * VDIM);
        bvA = vp[tid]; bvB = vp[tid + 256];
    }
    xs[0][aq + 0][arow] = avA.x; xs[0][aq + 1][arow] = avA.y;
    xs[0][aq + 2][arow] = avA.z; xs[0][aq + 3][arow] = avA.w;
    xs[0][aq + 4][arow] = avB.x; xs[0][aq + 5][arow] = avB.y;
    xs[0][aq + 6][arow] = avB.z; xs[0][aq + 7][arow] = avB.w;
    *(float4*)&vs[0][brow][bcol]     = bvA;
    *(float4*)&vs[0][brow + 8][bcol] = bvB;
    __syncthreads();

    const int NT = KSL / 16;   // 32
    for (int t = 0; t < NT; ++t) {
        int cur = t & 1;
        if (t + 1 < NT) {
            const float* xp = xsrc + (t + 1) * 16;
            avA = *(const float4*)(xp);
            avB = *(const float4*)(xp + 4);
            const float4* vp = (const float4*)(V + (size_t)(kstart + (t + 1) * 16) * VDIM);
            bvA = vp[tid]; bvB = vp[tid + 256];
        }
        #pragma unroll
        for (int kk = 0; kk < 16; ++kk) {
            float4 a0 = *(const float4*)&xs[cur][kk][r0];
            float4 a1 = *(const float4*)&xs[cur][kk][r0 + 64];
            float4 b0 = *(const float4*)&vs[cur][kk][c0];
            float4 b1 = *(const float4*)&vs[cur][kk][c0 + 64];
            float ar0[4] = {a0.x, a0.y, a0.z, a0.w};
            float ar1[4] = {a1.x, a1.y, a1.z, a1.w};
            #pragma unroll
            for (int i = 0; i < 4; ++i) {
                FMA4(acc[0][0][i], ar0[i], b0);
                FMA4(acc[0][1][i], ar0[i], b1);
                FMA4(acc[1][0][i], ar1[i], b0);
                FMA4(acc[1][1][i], ar1[i], b1);
            }
        }
        if (t + 1 == NT) break;
        int nxt = cur ^ 1;
        xs[nxt][aq + 0][arow] = avA.x; xs[nxt][aq + 1][arow] = avA.y;
        xs[nxt][aq + 2][arow] = avA.z; xs[nxt][aq + 3][arow] = avA.w;
        xs[nxt][aq + 4][arow] = avB.x; xs[nxt][aq + 5][arow] = avB.y;
        xs[nxt][aq + 6][arow] = avB.z; xs[nxt][aq + 7][arow] = avB.w;
        *(float4*)&vs[nxt][brow][bcol]     = bvA;
        *(float4*)&vs[nxt][brow + 8][bcol] = bvB;
        __syncthreads();
    }

    #pragma unroll
    for (int qr = 0; qr < 2; ++qr)
        #pragma unroll
        for (int i = 0; i < 4; ++i) {
            size_t row = rowbase + qr * 64 + r0 + i;
            *(float4*)(P + row * VDIM + c0)      = acc[qr][0][i];
            *(float4*)(P + row * VDIM + c0 + 64) = acc[qr][1][i];
        }
}

// ---------------------------------------------------------------------------
// 5) P = sum of SPLITK partials (Pp lives in d_out; P lives in ws so k_out
//    can safely overwrite d_out).
// ---------------------------------------------------------------------------
__global__ __launch_bounds__(256) void k_reduce(const float* __restrict__ Pp,
                                                float* __restrict__ P) {
    size_t idx = ((size_t)blockIdx.x * 256 + threadIdx.x) * 4;
    float4 a = *(const float4*)(Pp + idx);
    float4 b = *(const float4*)(Pp + (size_t)NR * VDIM + idx);
    float4 c = *(const float4*)(Pp + (size_t)2 * NR * VDIM + idx);
    float4 d = *(const float4*)(Pp + (size_t)3 * NR * VDIM + idx);
    float4 o;
    o.x = (a.x + b.x) + (c.x + d.x);
    o.y = (a.y + b.y) + (c.y + d.y);
    o.z = (a.z + b.z) + (c.z + d.z);
    o.w = (a.w + b.w) + (c.w + d.w);
    *(float4*)(P + idx) = o;
}

// ---------------------------------------------------------------------------
// 6) out = x - P @ W + by.  128x128 tile, BK=16, double-buffered like k_P.
// ---------------------------------------------------------------------------
__global__ __launch_bounds__(256) void k_out(const float* __restrict__ X,
                                             const float* __restrict__ P,
                                             const float* __restrict__ W,
                                             const float* __restrict__ by,
                                             float* __restrict__ out) {
    __shared__ float st[2][16][132];   // P^T tile [k][row], pad 4
    __shared__ float vt[2][16][132];   // W tile  [k][col], pad 4
    int tid = threadIdx.x;
    int rb = blockIdx.y * 128;
    int cb = blockIdx.x * 128;
    int r0 = (tid >> 4) << 2;
    int c0 = (tid & 15) << 2;

    int srow = tid >> 1;            // 0..127
    int sq   = (tid & 1) << 3;      // 0 or 8
    int vk   = tid >> 4;            // 0..15
    int vm   = (tid & 15) << 3;     // 0..120

    float4 acc[2][2][4];
    #pragma unroll
    for (int a = 0; a < 2; ++a)
        #pragma unroll
        for (int b = 0; b < 2; ++b)
            #pragma unroll
            for (int i = 0; i < 4; ++i) acc[a][b][i] = make_float4(0.f, 0.f, 0.f, 0.f);

    const float* ssrc  = P + (size_t)(rb + srow) * VDIM + sq;
    const float* vtsrc = W + (size_t)vk * CIN + cb + vm;

    float4 sA, sB, vA, vB;
    sA = *(const float4*)(ssrc);
    sB = *(const float4*)(ssrc + 4);
    vA = *(const float4*)(vtsrc);
    vB = *(const float4*)(vtsrc + 4);
    st[0][sq + 0][srow] = sA.x; st[0][sq + 1][srow] = sA.y;
    st[0][sq + 2][srow] = sA.z; st[0][sq + 3][srow] = sA.w;
    st[0][sq + 4][srow] = sB.x; st[0][sq + 5][srow] = sB.y;
    st[0][sq + 6][srow] = sB.z; st[0][sq + 7][srow] = sB.w;
    *(float4*)&vt[0][vk][vm]     = vA;
    *(float4*)&vt[0][vk][vm + 4] = vB;
    __syncthreads();

    const int NT = VDIM / 16;   // 8
    for (int t = 0; t < NT; ++t) {
        int cur = t & 1;
        if (t + 1 < NT) {
            const float* sp = ssrc + (t + 1) * 16;
            sA = *(const float4*)(sp);
            sB = *(const float4*)(sp + 4);
            const float* vp = vtsrc + (size_t)(t + 1) * 16 * CIN;
            vA = *(const float4*)(vp);
            vB = *(const float4*)(vp + 4);
        }
        #pragma unroll
        for (int kk = 0; kk < 16; ++kk) {
            float4 a0 = *(const float4*)&st[cur][kk][r0];
            float4 a1 = *(const float4*)&st[cur][kk][r0 + 64];
            float4 b0 = *(const float4*)&vt[cur][kk][c0];
            float4 b1 = *(const float4*)&vt[cur][kk][c0 + 64];
            float ar0[4] = {a0.x, a0.y, a0.z, a0.w};
            float ar1[4] = {a1.x, a1.y, a1.z, a1.w};
            #pragma unroll
            for (int i = 0; i < 4; ++i) {
                FMA4(acc[0][0][i], ar0[i], b0);
                FMA4(acc[0][1][i], ar0[i], b1);
                FMA4(acc[1][0][i], ar1[i], b0);
                FMA4(acc[1][1][i], ar1[i], b1);
            }
        }
        if (t + 1 == NT) break;
        int nxt = cur ^ 1;
        st[nxt][sq + 0][srow] = sA.x; st[nxt][sq + 1][srow] = sA.y;
        st[nxt][sq + 2][srow] = sA.z; st[nxt][sq + 3][srow] = sA.w;
        st[nxt][sq + 4][srow] = sB.x; st[nxt][sq + 5][srow] = sB.y;
        st[nxt][sq + 6][srow] = sB.z; st[nxt][sq + 7][srow] = sB.w;
        *(float4*)&vt[nxt][vk][vm]     = vA;
        *(float4*)&vt[nxt][vk][vm + 4] = vB;
        __syncthreads();
    }

    float4 by0 = *(const float4*)(by + cb + c0);
    float4 by1 = *(const float4*)(by + cb + c0 + 64);
    #pragma unroll
    for (int qr = 0; qr < 2; ++qr)
        #pragma unroll
        for (int i = 0; i < 4; ++i) {
            size_t row = rb + qr * 64 + r0 + i;
            float4 xv0 = *(const float4*)(X + row * CIN + cb + c0);
            float4 xv1 = *(const float4*)(X + row * CIN + cb + c0 + 64);
            float4 o0, o1;
            o0.x = xv0.x - acc[qr][0][i].x + by0.x;
            o0.y = xv0.y - acc[qr][0][i].y + by0.y;
            o0.z = xv0.z - acc[qr][0][i].z + by0.z;
            o0.w = xv0.w - acc[qr][0][i].w + by0.w;
            o1.x = xv1.x - acc[qr][1][i].x + by1.x;
            o1.y = xv1.y - acc[qr][1][i].y + by1.y;
            o1.z = xv1.z - acc[qr][1][i].z + by1.z;
            o1.w = xv1.w - acc[qr][1][i].w + by1.w;
            *(float4*)(out + row * CIN + cb + c0)      = o0;
            *(float4*)(out + row * CIN + cb + c0 + 64) = o1;
        }
}

// ---------------------------------------------------------------------------
extern "C" void kernel_launch(void* const* d_in, const int* in_sizes, int n_in,
                              void* d_out, int out_size, void* d_ws, size_t ws_size,
                              hipStream_t stream) {
    const float* x  = (const float*)d_in[0];   // [16384][2048]
    const float* Fq = (const float*)d_in[1];   // [2048][128]
    const float* by = (const float*)d_in[2];   // [2048]
    float* out = (float*)d_out;
    float* ws = (float*)d_ws;

    float* V  = ws;                    // 262144
    float* Vt = ws + 262144;           // 262144
    float* G  = ws + 524288;           // 16384
    float* W  = ws + 540672;           // 262144
    float* P  = ws + 802816;           // 2097152   (total 11.6 MB)
    // Split-K partials of P live in d_out (4 x 8.4 MB << 134 MB); k_reduce
    // moves the sum into ws P before k_out overwrites d_out.
    float* Pp = out;

    k_normalize<<<VDIM, 256, 0, stream>>>(Fq, V, Vt);
    k_gram<<<dim3(VDIM, VDIM), 64, 0, stream>>>(Vt, G);
    k_P<<<dim3(NR / 128, SPLITK), 256, 0, stream>>>(x, V, Pp);
    k_W<<<CIN / 128, 128, 0, stream>>>(Vt, G, W);
    k_reduce<<<(NR * VDIM) / 1024, 256, 0, stream>>>(Pp, P);
    k_out<<<dim3(CIN / 128, NR / 128), 256, 0, stream>>>(x, P, W, by, out);
}

// Round 7
// 447.373 us; speedup vs baseline: 1.4927x; 1.4927x over previous
//
#include <hip/hip_runtime.h>

#define NR   16384
#define CIN  2048
#define VDIM 128
#define SPLITK 4
#define KSL  (CIN / SPLITK)   // 512

#define FMA4(accv, s, bv) { accv.x += (s)*(bv).x; accv.y += (s)*(bv).y; accv.z += (s)*(bv).z; accv.w += (s)*(bv).w; }

// ---------------------------------------------------------------------------
// 1) Normalize columns of Fq -> V [CIN][VDIM] and Vt [VDIM][CIN]
// ---------------------------------------------------------------------------
__global__ __launch_bounds__(256) void k_normalize(const float* __restrict__ Fq,
                                                   float* __restrict__ V,
                                                   float* __restrict__ Vt) {
    int k = blockIdx.x;            // column index
    __shared__ float red[256];
    float ss = 0.f;
    for (int i = threadIdx.x; i < CIN; i += 256) {
        float v = Fq[i * VDIM + k];
        ss += v * v;
    }
    red[threadIdx.x] = ss;
    __syncthreads();
    for (int off = 128; off > 0; off >>= 1) {
        if (threadIdx.x < off) red[threadIdx.x] += red[threadIdx.x + off];
        __syncthreads();
    }
    float inv = 1.0f / sqrtf(red[0]);
    for (int i = threadIdx.x; i < CIN; i += 256) {
        float v = Fq[i * VDIM + k] * inv;
        V[i * VDIM + k] = v;
        Vt[k * CIN + i] = v;
    }
}

// ---------------------------------------------------------------------------
// 2) G2[j][k] = 2 * (v_j . v_k)  (prescaled Gram; consumed only by k_W)
// ---------------------------------------------------------------------------
__global__ __launch_bounds__(64) void k_gram(const float* __restrict__ Vt,
                                             float* __restrict__ G2) {
    int j = blockIdx.x, k = blockIdx.y;
    int lane = threadIdx.x;
    const float* a = Vt + j * CIN;
    const float* b = Vt + k * CIN;
    float s = 0.f;
    for (int i = lane * 4; i < CIN; i += 64 * 4) {
        float4 av = *(const float4*)(a + i);
        float4 bv = *(const float4*)(b + i);
        s += av.x * bv.x + av.y * bv.y + av.z * bv.z + av.w * bv.w;
    }
    #pragma unroll
    for (int off = 32; off > 0; off >>= 1) s += __shfl_down(s, off, 64);
    if (lane == 0) G2[j * VDIM + k] = 2.f * s;
}

// ---------------------------------------------------------------------------
// 3) W = M^{-1} (2 Vt),  M = I + 2*strictUpper(G)  (unit upper-triangular).
//    Lane-distributed back substitution: lane l holds w[l] (lo) and w[64+l]
//    (hi) for 4 columns. Per step j (descending): w[j] is FINAL in one lane;
//    broadcast it (1 shfl), then every lane i<j does one predicated FMA with
//    G2[j][i] (symmetric -> contiguous row, prefetched off the chain).
//    No butterfly reduce, no unroll blowup: chain = 128 * (shfl + fma).
// ---------------------------------------------------------------------------
__global__ __launch_bounds__(256) void k_W(const float* __restrict__ V,
                                           const float* __restrict__ G2,
                                           float* __restrict__ W) {
    int lane = threadIdx.x & 63;
    int wv = threadIdx.x >> 6;
    int c0 = (blockIdx.x * 4 + wv) * 4;     // 4 columns per wave

    float wlo[4], whi[4];
    #pragma unroll
    for (int r = 0; r < 4; ++r) {           // w[k] = 2*v_k[c] = 2*V[c*128+k]
        wlo[r] = 2.f * V[(size_t)(c0 + r) * VDIM + lane];
        whi[r] = 2.f * V[(size_t)(c0 + r) * VDIM + 64 + lane];
    }

    const float* g127 = G2 + 127 * VDIM;
    float glo = g127[lane], ghi = g127[64 + lane];
    for (int j = 127; j >= 1; --j) {
        float g_lo = glo, g_hi = ghi;
        if (j > 1) {                        // prefetch next G2 row (off-chain)
            const float* gn = G2 + (j - 1) * VDIM;
            glo = gn[lane]; ghi = gn[64 + lane];
        }
        float wj[4];
        #pragma unroll
        for (int r = 0; r < 4; ++r) {
            float src = (j >= 64) ? whi[r] : wlo[r];   // uniform branch
            wj[r] = __shfl(src, j & 63, 64);
        }
        #pragma unroll
        for (int r = 0; r < 4; ++r) {
            if (lane < j)      wlo[r] -= g_lo * wj[r];
            if (64 + lane < j) whi[r] -= g_hi * wj[r];
        }
    }

    #pragma unroll
    for (int r = 0; r < 4; ++r) {
        W[(size_t)lane * CIN + c0 + r]        = wlo[r];
        W[(size_t)(64 + lane) * CIN + c0 + r] = whi[r];
    }
}

// ---------------------------------------------------------------------------
// 4) P_y = x[:, y*512:(y+1)*512] @ V[y*512:(y+1)*512, :]   (split-K partials)
//    128x128 block tile, BK=16, 8x8 register tile, double-buffered LDS.
// ---------------------------------------------------------------------------
__global__ __launch_bounds__(256) void k_P(const float* __restrict__ X,
                                           const float* __restrict__ V,
                                           float* __restrict__ Pp) {
    __shared__ float xs[2][16][132];   // A^T tile [k][row], pad 4
    __shared__ float vs[2][16][132];   // B tile  [k][col], pad 4
    int tid = threadIdx.x;
    int rowbase = blockIdx.x * 128;
    int kstart = blockIdx.y * KSL;
    float* P = Pp + (size_t)blockIdx.y * NR * VDIM;

    int r0 = (tid >> 4) << 2;       // 0..60
    int c0 = (tid & 15) << 2;       // 0..60
    int arow = tid >> 1;            // 0..127
    int aq   = (tid & 1) << 3;      // 0 or 8
    int brow = tid >> 5;            // 0..7
    int bcol = (tid & 31) << 2;     // 0..124

    float4 acc[2][2][4];
    #pragma unroll
    for (int a = 0; a < 2; ++a)
        #pragma unroll
        for (int b = 0; b < 2; ++b)
            #pragma unroll
            for (int i = 0; i < 4; ++i) acc[a][b][i] = make_float4(0.f, 0.f, 0.f, 0.f);

    const float* xsrc = X + (size_t)(rowbase + arow) * CIN + kstart + aq;

    float4 avA, avB, bvA, bvB;
    avA = *(const float4*)(xsrc);
    avB = *(const float4*)(xsrc + 4);
    {
        const float4* vp = (const float4*)(V + (size_t)kstart * VDIM);
        bvA = vp[tid]; bvB = vp[tid + 256];
    }
    xs[0][aq + 0][arow] = avA.x; xs[0][aq + 1][arow] = avA.y;
    xs[0][aq + 2][arow] = avA.z; xs[0][aq + 3][arow] = avA.w;
    xs[0][aq + 4][arow] = avB.x; xs[0][aq + 5][arow] = avB.y;
    xs[0][aq + 6][arow] = avB.z; xs[0][aq + 7][arow] = avB.w;
    *(float4*)&vs[0][brow][bcol]     = bvA;
    *(float4*)&vs[0][brow + 8][bcol] = bvB;
    __syncthreads();

    const int NT = KSL / 16;   // 32
    for (int t = 0; t < NT; ++t) {
        int cur = t & 1;
        if (t + 1 < NT) {
            const float* xp = xsrc + (t + 1) * 16;
            avA = *(const float4*)(xp);
            avB = *(const float4*)(xp + 4);
            const float4* vp = (const float4*)(V + (size_t)(kstart + (t + 1) * 16) * VDIM);
            bvA = vp[tid]; bvB = vp[tid + 256];
        }
        #pragma unroll
        for (int kk = 0; kk < 16; ++kk) {
            float4 a0 = *(const float4*)&xs[cur][kk][r0];
            float4 a1 = *(const float4*)&xs[cur][kk][r0 + 64];
            float4 b0 = *(const float4*)&vs[cur][kk][c0];
            float4 b1 = *(const float4*)&vs[cur][kk][c0 + 64];
            float ar0[4] = {a0.x, a0.y, a0.z, a0.w};
            float ar1[4] = {a1.x, a1.y, a1.z, a1.w};
            #pragma unroll
            for (int i = 0; i < 4; ++i) {
                FMA4(acc[0][0][i], ar0[i], b0);
                FMA4(acc[0][1][i], ar0[i], b1);
                FMA4(acc[1][0][i], ar1[i], b0);
                FMA4(acc[1][1][i], ar1[i], b1);
            }
        }
        if (t + 1 == NT) break;
        int nxt = cur ^ 1;
        xs[nxt][aq + 0][arow] = avA.x; xs[nxt][aq + 1][arow] = avA.y;
        xs[nxt][aq + 2][arow] = avA.z; xs[nxt][aq + 3][arow] = avA.w;
        xs[nxt][aq + 4][arow] = avB.x; xs[nxt][aq + 5][arow] = avB.y;
        xs[nxt][aq + 6][arow] = avB.z; xs[nxt][aq + 7][arow] = avB.w;
        *(float4*)&vs[nxt][brow][bcol]     = bvA;
        *(float4*)&vs[nxt][brow + 8][bcol] = bvB;
        __syncthreads();
    }

    #pragma unroll
    for (int qr = 0; qr < 2; ++qr)
        #pragma unroll
        for (int i = 0; i < 4; ++i) {
            size_t row = rowbase + qr * 64 + r0 + i;
            *(float4*)(P + row * VDIM + c0)      = acc[qr][0][i];
            *(float4*)(P + row * VDIM + c0 + 64) = acc[qr][1][i];
        }
}

// ---------------------------------------------------------------------------
// 5) P = sum of SPLITK partials (Pp lives in d_out; P lives in ws so k_out
//    can safely overwrite d_out).
// ---------------------------------------------------------------------------
__global__ __launch_bounds__(256) void k_reduce(const float* __restrict__ Pp,
                                                float* __restrict__ P) {
    size_t idx = ((size_t)blockIdx.x * 256 + threadIdx.x) * 4;
    float4 a = *(const float4*)(Pp + idx);
    float4 b = *(const float4*)(Pp + (size_t)NR * VDIM + idx);
    float4 c = *(const float4*)(Pp + (size_t)2 * NR * VDIM + idx);
    float4 d = *(const float4*)(Pp + (size_t)3 * NR * VDIM + idx);
    float4 o;
    o.x = (a.x + b.x) + (c.x + d.x);
    o.y = (a.y + b.y) + (c.y + d.y);
    o.z = (a.z + b.z) + (c.z + d.z);
    o.w = (a.w + b.w) + (c.w + d.w);
    *(float4*)(P + idx) = o;
}

// ---------------------------------------------------------------------------
// 6) out = x - P @ W + by.  128x128 tile, BK=16, double-buffered like k_P.
// ---------------------------------------------------------------------------
__global__ __launch_bounds__(256) void k_out(const float* __restrict__ X,
                                             const float* __restrict__ P,
                                             const float* __restrict__ W,
                                             const float* __restrict__ by,
                                             float* __restrict__ out) {
    __shared__ float st[2][16][132];   // P^T tile [k][row], pad 4
    __shared__ float vt[2][16][132];   // W tile  [k][col], pad 4
    int tid = threadIdx.x;
    int rb = blockIdx.y * 128;
    int cb = blockIdx.x * 128;
    int r0 = (tid >> 4) << 2;
    int c0 = (tid & 15) << 2;

    int srow = tid >> 1;            // 0..127
    int sq   = (tid & 1) << 3;      // 0 or 8
    int vk   = tid >> 4;            // 0..15
    int vm   = (tid & 15) << 3;     // 0..120

    float4 acc[2][2][4];
    #pragma unroll
    for (int a = 0; a < 2; ++a)
        #pragma unroll
        for (int b = 0; b < 2; ++b)
            #pragma unroll
            for (int i = 0; i < 4; ++i) acc[a][b][i] = make_float4(0.f, 0.f, 0.f, 0.f);

    const float* ssrc  = P + (size_t)(rb + srow) * VDIM + sq;
    const float* vtsrc = W + (size_t)vk * CIN + cb + vm;

    float4 sA, sB, vA, vB;
    sA = *(const float4*)(ssrc);
    sB = *(const float4*)(ssrc + 4);
    vA = *(const float4*)(vtsrc);
    vB = *(const float4*)(vtsrc + 4);
    st[0][sq + 0][srow] = sA.x; st[0][sq + 1][srow] = sA.y;
    st[0][sq + 2][srow] = sA.z; st[0][sq + 3][srow] = sA.w;
    st[0][sq + 4][srow] = sB.x; st[0][sq + 5][srow] = sB.y;
    st[0][sq + 6][srow] = sB.z; st[0][sq + 7][srow] = sB.w;
    *(float4*)&vt[0][vk][vm]     = vA;
    *(float4*)&vt[0][vk][vm + 4] = vB;
    __syncthreads();

    const int NT = VDIM / 16;   // 8
    for (int t = 0; t < NT; ++t) {
        int cur = t & 1;
        if (t + 1 < NT) {
            const float* sp = ssrc + (t + 1) * 16;
            sA = *(const float4*)(sp);
            sB = *(const float4*)(sp + 4);
            const float* vp = vtsrc + (size_t)(t + 1) * 16 * CIN;
            vA = *(const float4*)(vp);
            vB = *(const float4*)(vp + 4);
        }
        #pragma unroll
        for (int kk = 0; kk < 16; ++kk) {
            float4 a0 = *(const float4*)&st[cur][kk][r0];
            float4 a1 = *(const float4*)&st[cur][kk][r0 + 64];
            float4 b0 = *(const float4*)&vt[cur][kk][c0];
            float4 b1 = *(const float4*)&vt[cur][kk][c0 + 64];
            float ar0[4] = {a0.x, a0.y, a0.z, a0.w};
            float ar1[4] = {a1.x, a1.y, a1.z, a1.w};
            #pragma unroll
            for (int i = 0; i < 4; ++i) {
                FMA4(acc[0][0][i], ar0[i], b0);
                FMA4(acc[0][1][i], ar0[i], b1);
                FMA4(acc[1][0][i], ar1[i], b0);
                FMA4(acc[1][1][i], ar1[i], b1);
            }
        }
        if (t + 1 == NT) break;
        int nxt = cur ^ 1;
        st[nxt][sq + 0][srow] = sA.x; st[nxt][sq + 1][srow] = sA.y;
        st[nxt][sq + 2][srow] = sA.z; st[nxt][sq + 3][srow] = sA.w;
        st[nxt][sq + 4][srow] = sB.x; st[nxt][sq + 5][srow] = sB.y;
        st[nxt][sq + 6][srow] = sB.z; st[nxt][sq + 7][srow] = sB.w;
        *(float4*)&vt[nxt][vk][vm]     = vA;
        *(float4*)&vt[nxt][vk][vm + 4] = vB;
        __syncthreads();
    }

    float4 by0 = *(const float4*)(by + cb + c0);
    float4 by1 = *(const float4*)(by + cb + c0 + 64);
    #pragma unroll
    for (int qr = 0; qr < 2; ++qr)
        #pragma unroll
        for (int i = 0; i < 4; ++i) {
            size_t row = rb + qr * 64 + r0 + i;
            float4 xv0 = *(const float4*)(X + row * CIN + cb + c0);
            float4 xv1 = *(const float4*)(X + row * CIN + cb + c0 + 64);
            float4 o0, o1;
            o0.x = xv0.x - acc[qr][0][i].x + by0.x;
            o0.y = xv0.y - acc[qr][0][i].y + by0.y;
            o0.z = xv0.z - acc[qr][0][i].z + by0.z;
            o0.w = xv0.w - acc[qr][0][i].w + by0.w;
            o1.x = xv1.x - acc[qr][1][i].x + by1.x;
            o1.y = xv1.y - acc[qr][1][i].y + by1.y;
            o1.z = xv1.z - acc[qr][1][i].z + by1.z;
            o1.w = xv1.w - acc[qr][1][i].w + by1.w;
            *(float4*)(out + row * CIN + cb + c0)      = o0;
            *(float4*)(out + row * CIN + cb + c0 + 64) = o1;
        }
}

// ---------------------------------------------------------------------------
extern "C" void kernel_launch(void* const* d_in, const int* in_sizes, int n_in,
                              void* d_out, int out_size, void* d_ws, size_t ws_size,
                              hipStream_t stream) {
    const float* x  = (const float*)d_in[0];   // [16384][2048]
    const float* Fq = (const float*)d_in[1];   // [2048][128]
    const float* by = (const float*)d_in[2];   // [2048]
    float* out = (float*)d_out;
    float* ws = (float*)d_ws;

    float* V  = ws;                    // 262144
    float* Vt = ws + 262144;           // 262144
    float* G2 = ws + 524288;           // 16384 (prescaled 2*Gram)
    float* W  = ws + 540672;           // 262144
    float* P  = ws + 802816;           // 2097152   (total 11.6 MB)
    // Split-K partials of P live in d_out (4 x 8.4 MB << 134 MB); k_reduce
    // moves the sum into ws P before k_out overwrites d_out.
    float* Pp = out;

    k_normalize<<<VDIM, 256, 0, stream>>>(Fq, V, Vt);
    k_gram<<<dim3(VDIM, VDIM), 64, 0, stream>>>(Vt, G2);
    k_P<<<dim3(NR / 128, SPLITK), 256, 0, stream>>>(x, V, Pp);
    k_W<<<CIN / 16, 256, 0, stream>>>(V, G2, W);
    k_reduce<<<(NR * VDIM) / 1024, 256, 0, stream>>>(Pp, P);
    k_out<<<dim3(CIN / 128, NR / 128), 256, 0, stream>>>(x, P, W, by, out);
}